// Round 5
// baseline (502.551 us; speedup 1.0000x reference)
//
#include <hip/hip_runtime.h>
#include <stdint.h>

#define BB 32
#define LL 1024
#define CC 512
#define NN (BB * LL)      // 32768 positions
#define NLEVS 4
#define OUTD 11
#define LPAD 8            // zero pad rows per sequence (>= max dilation)
#define LROWS (LL + LPAD) // 1032 padded rows per sequence

typedef __attribute__((ext_vector_type(8))) short bf16x8;
typedef __attribute__((ext_vector_type(4))) float f32x4;

static __device__ __forceinline__ unsigned short f2bf(float f) {
    union { float f; uint32_t u; } v; v.f = f;
    uint32_t u = v.u;
    uint32_t r = (u + 0x7fffu + ((u >> 16) & 1u)) >> 16;  // RNE
    return (unsigned short)r;
}
static __device__ __forceinline__ float bf2f(unsigned short h) {
    union { uint32_t u; float f; } v; v.u = ((uint32_t)h) << 16;
    return v.f;
}

// async 16B global -> LDS (wave-uniform LDS base + lane*16)
static __device__ __forceinline__ void llds16(const unsigned short* g, unsigned short* l) {
    __builtin_amdgcn_global_load_lds(
        (const __attribute__((address_space(1))) unsigned int*)g,
        (__attribute__((address_space(3))) unsigned int*)l, 16, 0, 0);
}

// Fused prep: pack_w | embed | zero_pad | pack_dw, selected by block range.
__global__ __launch_bounds__(256) void prep_kernel(
    const int* __restrict__ x, const float* __restrict__ emb,
    const float* __restrict__ w1, const float* __restrict__ w2,
    const float* __restrict__ dw,
    unsigned short* __restrict__ Hb0, unsigned short* __restrict__ Hb1,
    unsigned short* __restrict__ WpT, unsigned short* __restrict__ dwp)
{
    int b = blockIdx.x;
    if (b < 16384) {
        // WpT[cv][j][co][h]; kidx=j*8+h; kidx<512 -> tap k=1 (current), else k=0
        int e = b * 256 + threadIdx.x;
        int cv = e >> 19;
        int r = e & 524287;
        int j = r >> 12;
        int co = (r >> 3) & 511;
        int h = r & 7;
        int kidx = j * 8 + h;
        int k = (kidx < 512) ? 1 : 0;
        int ci = kidx & 511;
        int lvl = cv >> 1;
        const float* w = (cv & 1) ? w2 : w1;
        WpT[e] = f2bf(w[(((size_t)(lvl * 512 + co) * 512) + ci) * 2 + k]);
    } else if (b < 24576) {
        int t = (b - 16384) * 256 + threadIdx.x;
        int n = t >> 6;
        int c8 = (t & 63) * 8;
        int idx = x[n];
        const float* src = emb + (size_t)idx * CC + c8;
        float4 v0 = *(const float4*)src;
        float4 v1 = *(const float4*)(src + 4);
        ushort4 a, bb;
        a.x = f2bf(v0.x); a.y = f2bf(v0.y); a.z = f2bf(v0.z); a.w = f2bf(v0.w);
        bb.x = f2bf(v1.x); bb.y = f2bf(v1.y); bb.z = f2bf(v1.z); bb.w = f2bf(v1.w);
        int prow = (n >> 10) * LROWS + LPAD + (n & (LL - 1));
        unsigned short* dst = Hb0 + (size_t)prow * CC + c8;
        *(ushort4*)dst = a;
        *(ushort4*)(dst + 4) = bb;
    } else if (b < 24704) {
        int t = (b - 24576) * 256 + threadIdx.x;   // 32768 uint4 stores
        unsigned short* base = (t >> 14) ? Hb1 : Hb0;
        int rem = t & 16383;
        int p = rem >> 9;
        int q = rem & 511;
        size_t off = (size_t)p * (LROWS * CC) + (size_t)q * 8;
        *(uint4*)(base + off) = (uint4){0u, 0u, 0u, 0u};
    } else {
        int e = (b - 24704) * 256 + threadIdx.x;   // 8192 halves
        int jb = e >> 7;
        int o = (e >> 3) & 15;
        int j = e & 7;
        dwp[e] = f2bf((o < OUTD) ? dw[o * CC + jb * 8 + j] : 0.f);
    }
}

// GEMM: out[n][co] = act( A-window . W + bias ), all activations bf16.
// Round-5: r4's 8-phase skeleton + the m196/m201 FINE INTERLEAVE. r4 failed
// (-coarse: all 21 VMEM ops bulk-issued at the it top, then 8 pure phases --
// exactly the "coarse phase-split" variant m196 measured as a REGRESSION).
// The isolated +28-41% lever is threading the staging issues through the
// phases so the VMEM pipe is continuously fed while MFMA runs.
// Config: 256n x 256co tile, 512 threads, 8 waves (2 n-stripes x 4 co),
// grid 256 = 1 block/CU.
// Per ci-block it (BK=64 halves => K=128 MAC: 2 taps x 64 ci):
//   - load ALL 16 B frags into regs (L2-hot WpT)
//   - vmcnt(16): B is the only thing newer than staging(it) (which was
//     issued spread through it-1's phases) -> stale, near-free wait
//   - barrier: everyone's staging(it) landed
//   - 8 phases p=(s,half): 4 ds_read_b128 -> issue ONE staging segment of
//     it+1 (phases 0-3; ws0's 17th seg at phase 4) -> s_barrier ->
//     lgkmcnt(0) -> sched_barrier -> setprio(1) -> 16 MFMA -> setprio(0)
//     -> s_barrier.
// Slot reuse safe: stg(it+1) targets slot (it+1)&1 = (it-1)&1, whose reads
// all completed by it-1's final phase barrier (each phase lgkmcnt(0)s its
// own ds_reads before its MFMA cluster).
// 16x16x32 MFMA; 128-B-pitch XOR-swizzled LDS (zero-conflict, carried from
// r3/r4); XCD swizzle: both co-blocks of an n-window share an XCD.
// HAS_RES: v = relu(relu(acc+b) + res_bf16); in-place-safe (lane-owned).
#define SROWS 136
#define PBUFH (SROWS * 64)   // halves per stripe slot: 136 rows x 64 = 17408 B
template <bool HAS_RES>
__global__ __launch_bounds__(512, 2) void conv_gemm(
    const unsigned short* __restrict__ Ain, const unsigned short* __restrict__ WpT,
    const float* __restrict__ bias, const unsigned short* __restrict__ resB,
    unsigned short* __restrict__ OutB, int d)
{
    __shared__ unsigned short sA[2 * 2 * PBUFH];  // [stripe][slot][136*64]

    const int tid = threadIdx.x;
    const int wave = tid >> 6, lane = tid & 63;
    const int g = wave >> 2;                  // n-stripe 0/1
    const int ws = wave & 3;                  // staging slice + co-stripe

    const int bid = blockIdx.x;               // 0..255
    const int xcd = bid & 7;
    const int local = bid >> 3;               // 0..31
    const int cb = local >> 4;                // 0..1
    const int nb = xcd + 8 * (local & 15);    // 0..127
    const int co0 = cb * 256;
    const int n0 = nb * 256;                  // 256-aligned: never crosses seq

    const int rbase = (n0 >> 10) * LROWS + LPAD + (n0 & (LL - 1));
    const int wm = g * 128;                   // stripe n-offset
    const int wn = ws * 64;                   // wave co-stripe
    const int lm = lane & 15, quad = lane >> 4;

    // staging lane decomposition: 8 rows x 8 chunks of 16B per llds16 (1 KB)
    const int r8 = lane >> 3;
    const int c8 = lane & 7;

    f32x4 acc[8][4];
#pragma unroll
    for (int i = 0; i < 8; ++i)
#pragma unroll
        for (int j = 0; j < 4; ++j) acc[i][j] = (f32x4){0.f, 0.f, 0.f, 0.f};

    unsigned short* pb = sA + g * (2 * PBUFH);
    const unsigned short* gAb =
        Ain + (size_t)(rbase - 8 + wm + r8) * CC + (c8 ^ r8) * 8;

    // one staging segment (seg = 8 rows x 1 KB) of ci-block `it` -> slot it&1
    auto issueSeg = [&](int it, int seg) {
        llds16(gAb + (size_t)it * 64 + (size_t)seg * 8 * CC,
               pb + (it & 1) * PBUFH + seg * 512);
    };
    // bulk issue (prologue only): this wave's 4-5 segments of ci-block 0
    {
        issueSeg(0, ws + 0);
        issueSeg(0, ws + 4);
        issueSeg(0, ws + 8);
        issueSeg(0, ws + 12);
        if (ws == 0) issueSeg(0, 16);
    }

    bf16x8 breg[4][4];

    for (int it = 0; it < 8; ++it) {
        const int jb0 = it * 8;
        // ALL 16 B frags for this it (L2-hot WpT).
#pragma unroll
        for (int s = 0; s < 4; ++s) {
            const int t = s >> 1, ks = s & 1;
            const int jb = t * 64 + jb0 + ks * 4 + quad;
            const unsigned short* bbase = WpT + ((size_t)jb * 512 + co0 + wn + lm) * 8;
#pragma unroll
            for (int nt = 0; nt < 4; ++nt)
                breg[s][nt] = *(const bf16x8*)(bbase + (size_t)nt * 16 * 8);
        }

        // drain own staging(it): B (16) is the only thing newer. staging(it)
        // was issued through it-1's phases -> stale -> near-free.
        __builtin_amdgcn_s_waitcnt(0x4F70);                    // vmcnt(16)
        __asm__ volatile("" ::: "memory");
        __builtin_amdgcn_s_barrier();        // everyone's staging(it) landed
        __asm__ volatile("" ::: "memory");

        const unsigned short* buf = pb + (it & 1) * PBUFH;

        // 8 phases: p = (s, half). s = t*2+ks (t=tap, ks=K32 slice),
        // half selects mt 0-3 / 4-7. Fine interleave: each phase also issues
        // one staging segment of it+1 before its barrier.
#pragma unroll
        for (int p = 0; p < 8; ++p) {
            const int s = p >> 1, hsel = p & 1;
            const int t = s >> 1, ks = s & 1;
            const int shift = t ? d : 0;
            const int rowoff = 8 - shift;
            const int key = (8 - shift + lm) & 7;
            const int cpos = ((ks * 4 + quad) ^ key);
            bf16x8 af[4];
#pragma unroll
            for (int q = 0; q < 4; ++q) {
                const int mt = hsel * 4 + q;
                af[q] = *(const bf16x8*)&buf[(rowoff + mt * 16 + lm) * 64 + cpos * 8];
            }
            if (it < 7) {
                if (p < 4) issueSeg(it + 1, ws + 4 * p);
                else if (p == 4 && ws == 0) issueSeg(it + 1, 16);
            }
            __builtin_amdgcn_s_barrier();
            __builtin_amdgcn_s_waitcnt(0xC07F);   // lgkmcnt(0)
            __builtin_amdgcn_sched_barrier(0);
            __builtin_amdgcn_s_setprio(1);
#pragma unroll
            for (int q = 0; q < 4; ++q)
#pragma unroll
                for (int nt = 0; nt < 4; ++nt)
                    acc[hsel * 4 + q][nt] = __builtin_amdgcn_mfma_f32_16x16x32_bf16(
                        af[q], breg[s][nt], acc[hsel * 4 + q][nt], 0, 0, 0);
            __builtin_amdgcn_s_setprio(0);
            __builtin_amdgcn_s_barrier();
        }
    }

    // epilogue: C/D layout col(co)=lane&15, row(n)=quad*4+reg
    float bv[4];
#pragma unroll
    for (int nt = 0; nt < 4; ++nt) bv[nt] = bias[co0 + wn + nt * 16 + lm];

#pragma unroll
    for (int mt = 0; mt < 8; ++mt) {
        int prow0 = rbase + wm + mt * 16 + quad * 4;
#pragma unroll
        for (int nt = 0; nt < 4; ++nt) {
            int co = co0 + wn + nt * 16 + lm;
#pragma unroll
            for (int r = 0; r < 4; ++r) {
                size_t off = (size_t)(prow0 + r) * CC + co;
                float v = acc[mt][nt][r] + bv[nt];
                v = fmaxf(v, 0.f);
                if (HAS_RES) {
                    v += bf2f(resB[off]);
                    v = fmaxf(v, 0.f);
                }
                OutB[off] = f2bf(v);
            }
        }
    }
}

// decode as per-wave MFMA mini-GEMM: M=16 n, N=16 o (11 real), K=512.
__global__ __launch_bounds__(256) void decode_kernel(
    const unsigned short* __restrict__ H, const unsigned short* __restrict__ dwp,
    const float* __restrict__ db, const int* __restrict__ mask,
    float* __restrict__ out)
{
    const int wave = threadIdx.x >> 6, lane = threadIdx.x & 63;
    const int lm = lane & 15, quad = lane >> 4;
    const int n0 = blockIdx.x * 64 + wave * 16;    // 64-aligned: no seq crossing
    const int prow = ((n0 + lm) >> 10) * LROWS + LPAD + ((n0 + lm) & (LL - 1));

    f32x4 acc = (f32x4){0.f, 0.f, 0.f, 0.f};
#pragma unroll
    for (int ks = 0; ks < 16; ++ks) {
        bf16x8 af = *(const bf16x8*)&H[(size_t)prow * CC + ks * 32 + quad * 8];
        bf16x8 bf = *(const bf16x8*)&dwp[((size_t)(ks * 4 + quad) * 16 + lm) * 8];
        acc = __builtin_amdgcn_mfma_f32_16x16x32_bf16(af, bf, acc, 0, 0, 0);
    }

    if (lm < OUTD) {
        float bo = db[lm];
#pragma unroll
        for (int r = 0; r < 4; ++r) {
            int n = n0 + quad * 4 + r;
            float v = (mask[n] != 0) ? (acc[r] + bo) : 0.f;
            out[(size_t)n * OUTD + lm] = v;
        }
    }
}

extern "C" void kernel_launch(void* const* d_in, const int* in_sizes, int n_in,
                              void* d_out, int out_size, void* d_ws, size_t ws_size,
                              hipStream_t stream)
{
    const int* x = (const int*)d_in[0];
    const int* mask = (const int*)d_in[1];   // jnp bool_ staged as int32
    const float* emb = (const float*)d_in[2];
    const float* w1 = (const float*)d_in[3];
    const float* b1 = (const float*)d_in[4];
    const float* w2 = (const float*)d_in[5];
    const float* b2 = (const float*)d_in[6];
    const float* dw = (const float*)d_in[7];
    const float* db = (const float*)d_in[8];
    float* out = (float*)d_out;

    char* ws = (char*)d_ws;
    const size_t HBB = (size_t)BB * LROWS * CC * 2;       // 33.8 MB (padded bf16)
    unsigned short* Hb0 = (unsigned short*)ws;
    unsigned short* Hb1 = (unsigned short*)(ws + HBB);
    unsigned short* WpT = (unsigned short*)(ws + 2 * HBB); // k-major bf16 weights, 8 MB
    unsigned short* dwp = (unsigned short*)(ws + 2 * HBB + (size_t)NLEVS * 2 * CC * 1024 * 2);

    prep_kernel<<<24736, 256, 0, stream>>>(x, emb, w1, w2, dw, Hb0, Hb1, WpT, dwp);

    const int grid = (CC / 256) * (NN / 256);   // 2 * 128 = 256 blocks = 1/CU
    for (int i = 0; i < NLEVS; ++i) {
        int d = 1 << i;
        const unsigned short* W1 = WpT + (size_t)(i * 2 + 0) * CC * 1024;
        const unsigned short* W2 = WpT + (size_t)(i * 2 + 1) * CC * 1024;
        // conv1: A=Hb0 -> Hb1
        conv_gemm<false><<<grid, 512, 0, stream>>>(Hb0, W1, b1 + i * CC, nullptr, Hb1, d);
        // conv2: A=Hb1, res=Hb0 (bf16), out=Hb0 (in place, lane-owned)
        conv_gemm<true><<<grid, 512, 0, stream>>>(Hb1, W2, b2 + i * CC, Hb0, Hb0, d);
    }
    decode_kernel<<<NN / 64, 256, 0, stream>>>(Hb0, dwp, db, mask, out);
}

// Round 8
// 396.858 us; speedup vs baseline: 1.2663x; 1.2663x over previous
//
#include <hip/hip_runtime.h>
#include <stdint.h>

#define BB 32
#define LL 1024
#define CC 512
#define NN (BB * LL)      // 32768 positions
#define NLEVS 4
#define OUTD 11
#define LPAD 8            // zero pad rows per sequence (>= max dilation)
#define LROWS (LL + LPAD) // 1032 padded rows per sequence

typedef __attribute__((ext_vector_type(8))) short bf16x8;
typedef __attribute__((ext_vector_type(4))) float f32x4;

static __device__ __forceinline__ unsigned short f2bf(float f) {
    union { float f; uint32_t u; } v; v.f = f;
    uint32_t u = v.u;
    uint32_t r = (u + 0x7fffu + ((u >> 16) & 1u)) >> 16;  // RNE
    return (unsigned short)r;
}
static __device__ __forceinline__ float bf2f(unsigned short h) {
    union { uint32_t u; float f; } v; v.u = ((uint32_t)h) << 16;
    return v.f;
}

// async 16B global -> LDS (wave-uniform LDS base + lane*16)
static __device__ __forceinline__ void llds16(const unsigned short* g, unsigned short* l) {
    __builtin_amdgcn_global_load_lds(
        (const __attribute__((address_space(1))) unsigned int*)g,
        (__attribute__((address_space(3))) unsigned int*)l, 16, 0, 0);
}

// Fused prep: pack_w | embed | zero_pad | pack_dw, selected by block range.
__global__ __launch_bounds__(256) void prep_kernel(
    const int* __restrict__ x, const float* __restrict__ emb,
    const float* __restrict__ w1, const float* __restrict__ w2,
    const float* __restrict__ dw,
    unsigned short* __restrict__ Hb0, unsigned short* __restrict__ Hb1,
    unsigned short* __restrict__ WpT, unsigned short* __restrict__ dwp)
{
    int b = blockIdx.x;
    if (b < 16384) {
        // WpT[cv][j][co][h]; kidx=j*8+h; kidx<512 -> tap k=1 (current), else k=0
        int e = b * 256 + threadIdx.x;
        int cv = e >> 19;
        int r = e & 524287;
        int j = r >> 12;
        int co = (r >> 3) & 511;
        int h = r & 7;
        int kidx = j * 8 + h;
        int k = (kidx < 512) ? 1 : 0;
        int ci = kidx & 511;
        int lvl = cv >> 1;
        const float* w = (cv & 1) ? w2 : w1;
        WpT[e] = f2bf(w[(((size_t)(lvl * 512 + co) * 512) + ci) * 2 + k]);
    } else if (b < 24576) {
        int t = (b - 16384) * 256 + threadIdx.x;
        int n = t >> 6;
        int c8 = (t & 63) * 8;
        int idx = x[n];
        const float* src = emb + (size_t)idx * CC + c8;
        float4 v0 = *(const float4*)src;
        float4 v1 = *(const float4*)(src + 4);
        ushort4 a, bb;
        a.x = f2bf(v0.x); a.y = f2bf(v0.y); a.z = f2bf(v0.z); a.w = f2bf(v0.w);
        bb.x = f2bf(v1.x); bb.y = f2bf(v1.y); bb.z = f2bf(v1.z); bb.w = f2bf(v1.w);
        int prow = (n >> 10) * LROWS + LPAD + (n & (LL - 1));
        unsigned short* dst = Hb0 + (size_t)prow * CC + c8;
        *(ushort4*)dst = a;
        *(ushort4*)(dst + 4) = bb;
    } else if (b < 24704) {
        int t = (b - 24576) * 256 + threadIdx.x;   // 32768 uint4 stores
        unsigned short* base = (t >> 14) ? Hb1 : Hb0;
        int rem = t & 16383;
        int p = rem >> 9;
        int q = rem & 511;
        size_t off = (size_t)p * (LROWS * CC) + (size_t)q * 8;
        *(uint4*)(base + off) = (uint4){0u, 0u, 0u, 0u};
    } else {
        int e = (b - 24704) * 256 + threadIdx.x;   // 8192 halves
        int jb = e >> 7;
        int o = (e >> 3) & 15;
        int j = e & 7;
        dwp[e] = f2bf((o < OUTD) ? dw[o * CC + jb * 8 + j] : 0.f);
    }
}

// GEMM: out[n][co] = act( A-window . W + bias ), all activations bf16.
// 128n x 128co tile, BK=64/buffer, 2 LDS slots. BARRIER-FREE K-loop:
// per wave/it: spin done[it-1]==4 -> issue A loads for it+1 ->
// s_waitcnt vmcnt(4|5) (drains it's loads only; it+1's stay in flight through
// the whole compute phase) -> ready[it]+=1 -> spin ready[it]==4 -> compute(it)
// -> done[it]+=1. No __syncthreads in the loop => no forced vmcnt(0) drain
// (the m97-plateau stall). 16x16x32 MFMA 4x4/wave; 128-B-pitch XOR-swizzled
// LDS (measured-zero-conflict geometry). B direct from global (k-major WpT).
// XCD swizzle: 4 co-blocks of an n-window land on one XCD.
// HAS_RES: v = relu(relu(acc+b) + res_bf16); in-place-safe (lane-owned elems).
//
// SESSION VERDICT (rounds 0-5): this structure is the measured optimum for
// this op. Five alternatives -- pair-private staging (r1), 256x128/2-blk with
// full B-preload + single counted drain (r3), 8-phase coarse + setprio (r4),
// 8-phase fine interleave (r5) -- measured 46.1 / 45.0 / 48.1 / 58.0 us vs
// 46.2 here, i.e. the documented T3/T4/T5 escapes REGRESS on this shape
// (K=1024 => only 8 BK-iterations: the deep-pipeline prologue and phase
// machinery don't amortize; m232's open quadrant). No pipe is saturated
// (MFMA 27%, VALU 24%, HBM 20%, conflicts 0): residual is correlated
// latency stall at ~90% of the m97-class structural ceiling for this shape.
#define BUFH (17 * 512)   // 136 rows x 64 halves = 17408 B per buffer
template <bool HAS_RES>
__global__ __launch_bounds__(256, 4) void conv_gemm(
    const unsigned short* __restrict__ Ain, const unsigned short* __restrict__ WpT,
    const float* __restrict__ bias, const unsigned short* __restrict__ resB,
    unsigned short* __restrict__ OutB, int d)
{
    __shared__ unsigned short sA[2 * BUFH];
    __shared__ int s_ready[8];
    __shared__ int s_done[8];

    const int tid = threadIdx.x;
    const int wave = tid >> 6, lane = tid & 63;

    const int bid = blockIdx.x;               // 0..1023
    const int xcd = bid & 7;
    const int local = bid >> 3;               // 0..127
    const int cb = local >> 5;                // 0..3
    const int nb = xcd + 8 * (local & 31);    // 0..255
    const int co0 = cb * 128;
    const int n0 = nb * 128;

    const int rbase = (n0 >> 10) * LROWS + LPAD + (n0 & (LL - 1));
    const int wm = (wave >> 1) * 64;           // wave n-stripe
    const int wn = (wave & 1) * 64;            // wave co-stripe
    const int lm = lane & 15, quad = lane >> 4;

    // staging lane decomposition: 8 rows x 8 chunks of 16B per llds16 (1 KB)
    const int r8 = lane >> 3;
    const int c8 = lane & 7;

    if (tid < 8) { s_ready[tid] = 0; s_done[tid] = 0; }
    __syncthreads();

    f32x4 acc[4][4];
#pragma unroll
    for (int i = 0; i < 4; ++i)
#pragma unroll
        for (int j = 0; j < 4; ++j) acc[i][j] = (f32x4){0.f, 0.f, 0.f, 0.f};

    // issue this wave's segments of ci-block `it` into slot it&1
    // wave0: segs 0,4,8,12,16 (5 loads); waves1-3: 4 loads
    auto issue = [&](int it) {
        const unsigned short* gA =
            Ain + (size_t)(rbase - 8 + r8) * CC + it * 64 + (c8 ^ r8) * 8;
        unsigned short* lbase = sA + (it & 1) * BUFH;
        for (int seg = wave; seg < 17; seg += 4)
            llds16(gA + (size_t)seg * 8 * CC, lbase + seg * 512);
    };
    auto spin4 = [&](int* p) {
        volatile int* vp = (volatile int*)p;
        while (*vp < 4) __builtin_amdgcn_s_sleep(1);
    };

    issue(0);

    for (int it = 0; it < 8; ++it) {
        if (it < 7) {
            if (it >= 1) spin4(&s_done[it - 1]);     // slot (it+1)&1 free?
            issue(it + 1);
            // drain it's loads only; leave it+1's in flight (wave0 issued 5)
            if (wave == 0) __builtin_amdgcn_s_waitcnt(0xF75);  // vmcnt(5)
            else           __builtin_amdgcn_s_waitcnt(0xF74);  // vmcnt(4)
        } else {
            __builtin_amdgcn_s_waitcnt(0xF70);                 // vmcnt(0)
        }
        __asm__ volatile("" ::: "memory");
        if (lane == 0) atomicAdd(&s_ready[it], 1);
        spin4(&s_ready[it]);
        __asm__ volatile("" ::: "memory");

        const unsigned short* buf = sA + (it & 1) * BUFH;
        const int jb0 = it * 8;

        // step s = t*2 + ks: t = tap (0 current, 1 past), ks = K=32 slice
        auto loadA = [&](int s, bf16x8* af) {
            const int t = s >> 1, ks = s & 1;
            const int shift = t ? d : 0;
            const int rowoff = 8 - shift + wm;
            const int key = (8 - shift + lm) & 7;
            const int cpos = ((ks * 4 + quad) ^ key);
#pragma unroll
            for (int mt = 0; mt < 4; ++mt)
                af[mt] = *(const bf16x8*)&buf[(rowoff + mt * 16 + lm) * 64 + cpos * 8];
        };
        auto loadB = [&](int s, bf16x8* bf) {
            const int t = s >> 1, ks = s & 1;
            const int jb = t * 64 + jb0 + ks * 4 + quad;
            const unsigned short* bbase = WpT + ((size_t)jb * 512 + co0 + wn + lm) * 8;
#pragma unroll
            for (int nt = 0; nt < 4; ++nt)
                bf[nt] = *(const bf16x8*)(bbase + (size_t)nt * 16 * 8);
        };

        bf16x8 afc[4], bfc[4], afn[4], bfn[4];
        loadA(0, afc);
        loadB(0, bfc);
#pragma unroll
        for (int s = 0; s < 4; ++s) {
            if (s < 3) { loadA(s + 1, afn); loadB(s + 1, bfn); }
#pragma unroll
            for (int mt = 0; mt < 4; ++mt)
#pragma unroll
                for (int nt = 0; nt < 4; ++nt)
                    acc[mt][nt] = __builtin_amdgcn_mfma_f32_16x16x32_bf16(
                        afc[mt], bfc[nt], acc[mt][nt], 0, 0, 0);
            if (s < 3) {
#pragma unroll
                for (int q2 = 0; q2 < 4; ++q2) { afc[q2] = afn[q2]; bfc[q2] = bfn[q2]; }
            }
        }

        __asm__ volatile("" ::: "memory");
        if (lane == 0) atomicAdd(&s_done[it], 1);
    }

    // epilogue: C/D layout col(co)=lane&15, row(n)=quad*4+reg
    float bv[4];
#pragma unroll
    for (int nt = 0; nt < 4; ++nt) bv[nt] = bias[co0 + wn + nt * 16 + lm];

#pragma unroll
    for (int mt = 0; mt < 4; ++mt) {
        int prow0 = rbase + wm + mt * 16 + quad * 4;
#pragma unroll
        for (int nt = 0; nt < 4; ++nt) {
            int co = co0 + wn + nt * 16 + lm;
#pragma unroll
            for (int r = 0; r < 4; ++r) {
                size_t off = (size_t)(prow0 + r) * CC + co;
                float v = acc[mt][nt][r] + bv[nt];
                v = fmaxf(v, 0.f);
                if (HAS_RES) {
                    v += bf2f(resB[off]);
                    v = fmaxf(v, 0.f);
                }
                OutB[off] = f2bf(v);
            }
        }
    }
}

// decode as per-wave MFMA mini-GEMM: M=16 n, N=16 o (11 real), K=512.
__global__ __launch_bounds__(256) void decode_kernel(
    const unsigned short* __restrict__ H, const unsigned short* __restrict__ dwp,
    const float* __restrict__ db, const int* __restrict__ mask,
    float* __restrict__ out)
{
    const int wave = threadIdx.x >> 6, lane = threadIdx.x & 63;
    const int lm = lane & 15, quad = lane >> 4;
    const int n0 = blockIdx.x * 64 + wave * 16;    // 64-aligned: no seq crossing
    const int prow = ((n0 + lm) >> 10) * LROWS + LPAD + ((n0 + lm) & (LL - 1));

    f32x4 acc = (f32x4){0.f, 0.f, 0.f, 0.f};
#pragma unroll
    for (int ks = 0; ks < 16; ++ks) {
        bf16x8 af = *(const bf16x8*)&H[(size_t)prow * CC + ks * 32 + quad * 8];
        bf16x8 bf = *(const bf16x8*)&dwp[((size_t)(ks * 4 + quad) * 16 + lm) * 8];
        acc = __builtin_amdgcn_mfma_f32_16x16x32_bf16(af, bf, acc, 0, 0, 0);
    }

    if (lm < OUTD) {
        float bo = db[lm];
#pragma unroll
        for (int r = 0; r < 4; ++r) {
            int n = n0 + quad * 4 + r;
            float v = (mask[n] != 0) ? (acc[r] + bo) : 0.f;
            out[(size_t)n * OUTD + lm] = v;
        }
    }
}

extern "C" void kernel_launch(void* const* d_in, const int* in_sizes, int n_in,
                              void* d_out, int out_size, void* d_ws, size_t ws_size,
                              hipStream_t stream)
{
    const int* x = (const int*)d_in[0];
    const int* mask = (const int*)d_in[1];   // jnp bool_ staged as int32
    const float* emb = (const float*)d_in[2];
    const float* w1 = (const float*)d_in[3];
    const float* b1 = (const float*)d_in[4];
    const float* w2 = (const float*)d_in[5];
    const float* b2 = (const float*)d_in[6];
    const float* dw = (const float*)d_in[7];
    const float* db = (const float*)d_in[8];
    float* out = (float*)d_out;

    char* ws = (char*)d_ws;
    const size_t HBB = (size_t)BB * LROWS * CC * 2;       // 33.8 MB (padded bf16)
    unsigned short* Hb0 = (unsigned short*)ws;
    unsigned short* Hb1 = (unsigned short*)(ws + HBB);
    unsigned short* WpT = (unsigned short*)(ws + 2 * HBB); // k-major bf16 weights, 8 MB
    unsigned short* dwp = (unsigned short*)(ws + 2 * HBB + (size_t)NLEVS * 2 * CC * 1024 * 2);

    prep_kernel<<<24736, 256, 0, stream>>>(x, emb, w1, w2, dw, Hb0, Hb1, WpT, dwp);

    const int grid = (CC / 128) * (NN / 128);   // 4 * 256 = 1024 blocks = 4/CU
    for (int i = 0; i < NLEVS; ++i) {
        int d = 1 << i;
        const unsigned short* W1 = WpT + (size_t)(i * 2 + 0) * CC * 1024;
        const unsigned short* W2 = WpT + (size_t)(i * 2 + 1) * CC * 1024;
        // conv1: A=Hb0 -> Hb1
        conv_gemm<false><<<grid, 256, 0, stream>>>(Hb0, W1, b1 + i * CC, nullptr, Hb1, d);
        // conv2: A=Hb1, res=Hb0 (bf16), out=Hb0 (in place, lane-owned)
        conv_gemm<true><<<grid, 256, 0, stream>>>(Hb1, W2, b2 + i * CC, Hb0, Hb0, d);
    }
    decode_kernel<<<NN / 64, 256, 0, stream>>>(Hb0, dwp, db, mask, out);
}

// Round 9
// 392.963 us; speedup vs baseline: 1.2789x; 1.0099x over previous
//
#include <hip/hip_runtime.h>
#include <stdint.h>

#define BB 32
#define LL 1024
#define CC 512
#define NN (BB * LL)      // 32768 positions
#define NLEVS 4
#define OUTD 11
#define LPAD 8            // zero pad rows per sequence (>= max dilation)
#define LROWS (LL + LPAD) // 1032 padded rows per sequence

typedef __attribute__((ext_vector_type(8))) short bf16x8;
typedef __attribute__((ext_vector_type(4))) float f32x4;

static __device__ __forceinline__ unsigned short f2bf(float f) {
    union { float f; uint32_t u; } v; v.f = f;
    uint32_t u = v.u;
    uint32_t r = (u + 0x7fffu + ((u >> 16) & 1u)) >> 16;  // RNE
    return (unsigned short)r;
}
static __device__ __forceinline__ float bf2f(unsigned short h) {
    union { uint32_t u; float f; } v; v.u = ((uint32_t)h) << 16;
    return v.f;
}

// async 16B global -> LDS (wave-uniform LDS base + lane*16)
static __device__ __forceinline__ void llds16(const unsigned short* g, unsigned short* l) {
    __builtin_amdgcn_global_load_lds(
        (const __attribute__((address_space(1))) unsigned int*)g,
        (__attribute__((address_space(3))) unsigned int*)l, 16, 0, 0);
}

// Fused prep: pack_w | embed | zero_pad | pack_dw, selected by block range.
__global__ __launch_bounds__(256) void prep_kernel(
    const int* __restrict__ x, const float* __restrict__ emb,
    const float* __restrict__ w1, const float* __restrict__ w2,
    const float* __restrict__ dw,
    unsigned short* __restrict__ Hb0, unsigned short* __restrict__ Hb1,
    unsigned short* __restrict__ WpT, unsigned short* __restrict__ dwp)
{
    int b = blockIdx.x;
    if (b < 16384) {
        // WpT[cv][j][co][h]; kidx=j*8+h; kidx<512 -> tap k=1 (current), else k=0
        int e = b * 256 + threadIdx.x;
        int cv = e >> 19;
        int r = e & 524287;
        int j = r >> 12;
        int co = (r >> 3) & 511;
        int h = r & 7;
        int kidx = j * 8 + h;
        int k = (kidx < 512) ? 1 : 0;
        int ci = kidx & 511;
        int lvl = cv >> 1;
        const float* w = (cv & 1) ? w2 : w1;
        WpT[e] = f2bf(w[(((size_t)(lvl * 512 + co) * 512) + ci) * 2 + k]);
    } else if (b < 24576) {
        int t = (b - 16384) * 256 + threadIdx.x;
        int n = t >> 6;
        int c8 = (t & 63) * 8;
        int idx = x[n];
        const float* src = emb + (size_t)idx * CC + c8;
        float4 v0 = *(const float4*)src;
        float4 v1 = *(const float4*)(src + 4);
        ushort4 a, bb;
        a.x = f2bf(v0.x); a.y = f2bf(v0.y); a.z = f2bf(v0.z); a.w = f2bf(v0.w);
        bb.x = f2bf(v1.x); bb.y = f2bf(v1.y); bb.z = f2bf(v1.z); bb.w = f2bf(v1.w);
        int prow = (n >> 10) * LROWS + LPAD + (n & (LL - 1));
        unsigned short* dst = Hb0 + (size_t)prow * CC + c8;
        *(ushort4*)dst = a;
        *(ushort4*)(dst + 4) = bb;
    } else if (b < 24704) {
        int t = (b - 24576) * 256 + threadIdx.x;   // 32768 uint4 stores
        unsigned short* base = (t >> 14) ? Hb1 : Hb0;
        int rem = t & 16383;
        int p = rem >> 9;
        int q = rem & 511;
        size_t off = (size_t)p * (LROWS * CC) + (size_t)q * 8;
        *(uint4*)(base + off) = (uint4){0u, 0u, 0u, 0u};
    } else {
        int e = (b - 24704) * 256 + threadIdx.x;   // 8192 halves
        int jb = e >> 7;
        int o = (e >> 3) & 15;
        int j = e & 7;
        dwp[e] = f2bf((o < OUTD) ? dw[o * CC + jb * 8 + j] : 0.f);
    }
}

// GEMM: out[n][co] = act( A-window . W + bias ), all activations bf16.
// FINAL SESSION CONFIG (r3 structure -- fastest measured conv dispatch):
// 256n x 128co tile, BK=64/buffer, grid 512 = 2 blocks/CU = 2 waves/SIMD.
// Measured 44.8-45.2 us/dispatch vs 46.1-46.2 for the 128x128/4-block
// variant; five other schedule classes (pair-private 128^2, 8-phase coarse
// +setprio, 8-phase fine interleave) measured equal or worse (46.1 / 48.1 /
// 58.0). Structural ceiling statement: 8-iteration K-loop with ~200-250 cyc
// L2-dependent operand fetch per iteration and <=4 independent wave contexts
// per SIMD; no pipe saturated (MFMA ~29%, HBM ~20%, L2 ~25%, LDS-conflict 0);
// the documented T3/T4 + fine-interleave escapes REGRESS at this K-depth
// (8 BK-its: pipeline prologue/phase machinery don't amortize).
// Key mechanics: B fully preloaded per-it into regs BEFORE the staging issue
// (in-order vmcnt retirement would otherwise force draining the prefetch to
// consume B); pair (same n-stripe) shares a private 136-row double-buffered
// LDS stripe, each wave issues ALL 17 segments itself (duplicate, race-benign)
// so readiness = own vmcnt(0) only; partner done-flag guards slot reuse.
// A-frags processed in two mt-halves (af[4]) keeping live regs ~235 < 256.
// 16x16x32 MFMA; 128-B-pitch XOR-swizzled LDS (zero-conflict); XCD swizzle:
// 4 co-blocks of an n-window share an XCD. HAS_RES: relu(relu(acc+b)+res),
// in-place-safe (lane-owned elements).
#define PSEG 17
#define SROWS 136
#define PBUFH (SROWS * 64)   // halves per pair slot: 136 rows x 64 = 17408 B
template <bool HAS_RES>
__global__ __launch_bounds__(256, 2) void conv_gemm(
    const unsigned short* __restrict__ Ain, const unsigned short* __restrict__ WpT,
    const float* __restrict__ bias, const unsigned short* __restrict__ resB,
    unsigned short* __restrict__ OutB, int d)
{
    __shared__ unsigned short sA[2 * 2 * PBUFH];  // [pair][slot][136*64]
    __shared__ int s_flag[4][8];                  // [wave][it] done-with-slot

    const int tid = threadIdx.x;
    const int wave = tid >> 6, lane = tid & 63;
    const int pairi = wave >> 1;

    const int bid = blockIdx.x;               // 0..511
    const int xcd = bid & 7;
    const int local = bid >> 3;               // 0..63
    const int cb = local >> 4;                // 0..3
    const int nb = xcd + 8 * (local & 15);    // 0..127
    const int co0 = cb * 128;
    const int n0 = nb * 256;                  // 256-aligned: never crosses seq

    const int rbase = (n0 >> 10) * LROWS + LPAD + (n0 & (LL - 1));
    const int wm = pairi * 128;                // pair n-stripe
    const int wn = (wave & 1) * 64;            // wave co-stripe
    const int lm = lane & 15, quad = lane >> 4;

    // staging lane decomposition: 8 rows x 8 chunks of 16B per llds16 (1 KB)
    const int r8 = lane >> 3;
    const int c8 = lane & 7;

    if (tid < 32) ((int*)s_flag)[tid] = 0;
    __syncthreads();

    f32x4 acc[8][4];
#pragma unroll
    for (int i = 0; i < 8; ++i)
#pragma unroll
        for (int j = 0; j < 4; ++j) acc[i][j] = (f32x4){0.f, 0.f, 0.f, 0.f};

    unsigned short* pb = sA + pairi * (2 * PBUFH);
    const unsigned short* gAb =
        Ain + (size_t)(rbase - 8 + wm + r8) * CC + (c8 ^ r8) * 8;

    // issue ALL 17 segments of ci-block `it` into this pair's slot it&1
    auto issue = [&](int it) {
        const unsigned short* gA = gAb + it * 64;
        unsigned short* lb = pb + (it & 1) * PBUFH;
#pragma unroll
        for (int seg = 0; seg < PSEG; ++seg)
            llds16(gA + (size_t)seg * 8 * CC, lb + seg * 512);
    };

    issue(0);

    bf16x8 breg[4][4];

    for (int it = 0; it < 8; ++it) {
        // own staging(it) is the only outstanding vmem; it had the whole
        // previous compute phase (> HBM latency) to land.
        __builtin_amdgcn_s_waitcnt(0xF70);                     // vmcnt(0)
        __asm__ volatile("" ::: "memory");

        const int jb0 = it * 8;
        // ALL B loads for this it BEFORE the next staging issue: anything
        // issued after a global_load_lds can't be waited for without draining
        // it (in-order vmcnt retirement).
#pragma unroll
        for (int s = 0; s < 4; ++s) {
            const int t = s >> 1, ks = s & 1;
            const int jb = t * 64 + jb0 + ks * 4 + quad;
            const unsigned short* bbase = WpT + ((size_t)jb * 512 + co0 + wn + lm) * 8;
#pragma unroll
            for (int nt = 0; nt < 4; ++nt)
                breg[s][nt] = *(const bf16x8*)(bbase + (size_t)nt * 16 * 8);
        }
        __asm__ volatile("" ::: "memory");

        if (it < 7) {
            if (it >= 1) {
                // slot (it+1)&1 was last read by partner at it-1
                volatile int* vp = &s_flag[wave ^ 1][it - 1];
                while (*vp == 0) __builtin_amdgcn_s_sleep(1);
            }
            issue(it + 1);   // stays in flight through the whole compute phase
        }
        __asm__ volatile("" ::: "memory");

        const unsigned short* buf = pb + (it & 1) * PBUFH;

        // step s = t*2 + ks: t = tap (0 current, 1 past), ks = K=32 slice.
        // Two mt-halves of 4 keep the live A-frag set at 16 VGPRs.
#pragma unroll
        for (int s = 0; s < 4; ++s) {
            const int t = s >> 1, ks = s & 1;
            const int shift = t ? d : 0;
            const int rowoff = 8 - shift;
            const int key = (8 - shift + lm) & 7;
            const int cpos = ((ks * 4 + quad) ^ key);
#pragma unroll
            for (int half = 0; half < 2; ++half) {
                bf16x8 af[4];
#pragma unroll
                for (int q = 0; q < 4; ++q) {
                    const int mt = half * 4 + q;
                    af[q] = *(const bf16x8*)&buf[(rowoff + mt * 16 + lm) * 64 + cpos * 8];
                }
#pragma unroll
                for (int q = 0; q < 4; ++q)
#pragma unroll
                    for (int nt = 0; nt < 4; ++nt)
                        acc[half * 4 + q][nt] = __builtin_amdgcn_mfma_f32_16x16x32_bf16(
                            af[q], breg[s][nt], acc[half * 4 + q][nt], 0, 0, 0);
            }
        }

        __asm__ volatile("" ::: "memory");
        if (lane == 0) *(volatile int*)&s_flag[wave][it] = 1;
    }

    // epilogue: C/D layout col(co)=lane&15, row(n)=quad*4+reg
    float bv[4];
#pragma unroll
    for (int nt = 0; nt < 4; ++nt) bv[nt] = bias[co0 + wn + nt * 16 + lm];

#pragma unroll
    for (int mt = 0; mt < 8; ++mt) {
        int prow0 = rbase + wm + mt * 16 + quad * 4;
#pragma unroll
        for (int nt = 0; nt < 4; ++nt) {
            int co = co0 + wn + nt * 16 + lm;
#pragma unroll
            for (int r = 0; r < 4; ++r) {
                size_t off = (size_t)(prow0 + r) * CC + co;
                float v = acc[mt][nt][r] + bv[nt];
                v = fmaxf(v, 0.f);
                if (HAS_RES) {
                    v += bf2f(resB[off]);
                    v = fmaxf(v, 0.f);
                }
                OutB[off] = f2bf(v);
            }
        }
    }
}

// decode as per-wave MFMA mini-GEMM: M=16 n, N=16 o (11 real), K=512.
__global__ __launch_bounds__(256) void decode_kernel(
    const unsigned short* __restrict__ H, const unsigned short* __restrict__ dwp,
    const float* __restrict__ db, const int* __restrict__ mask,
    float* __restrict__ out)
{
    const int wave = threadIdx.x >> 6, lane = threadIdx.x & 63;
    const int lm = lane & 15, quad = lane >> 4;
    const int n0 = blockIdx.x * 64 + wave * 16;    // 64-aligned: no seq crossing
    const int prow = ((n0 + lm) >> 10) * LROWS + LPAD + ((n0 + lm) & (LL - 1));

    f32x4 acc = (f32x4){0.f, 0.f, 0.f, 0.f};
#pragma unroll
    for (int ks = 0; ks < 16; ++ks) {
        bf16x8 af = *(const bf16x8*)&H[(size_t)prow * CC + ks * 32 + quad * 8];
        bf16x8 bf = *(const bf16x8*)&dwp[((size_t)(ks * 4 + quad) * 16 + lm) * 8];
        acc = __builtin_amdgcn_mfma_f32_16x16x32_bf16(af, bf, acc, 0, 0, 0);
    }

    if (lm < OUTD) {
        float bo = db[lm];
#pragma unroll
        for (int r = 0; r < 4; ++r) {
            int n = n0 + quad * 4 + r;
            float v = (mask[n] != 0) ? (acc[r] + bo) : 0.f;
            out[(size_t)n * OUTD + lm] = v;
        }
    }
}

extern "C" void kernel_launch(void* const* d_in, const int* in_sizes, int n_in,
                              void* d_out, int out_size, void* d_ws, size_t ws_size,
                              hipStream_t stream)
{
    const int* x = (const int*)d_in[0];
    const int* mask = (const int*)d_in[1];   // jnp bool_ staged as int32
    const float* emb = (const float*)d_in[2];
    const float* w1 = (const float*)d_in[3];
    const float* b1 = (const float*)d_in[4];
    const float* w2 = (const float*)d_in[5];
    const float* b2 = (const float*)d_in[6];
    const float* dw = (const float*)d_in[7];
    const float* db = (const float*)d_in[8];
    float* out = (float*)d_out;

    char* ws = (char*)d_ws;
    const size_t HBB = (size_t)BB * LROWS * CC * 2;       // 33.8 MB (padded bf16)
    unsigned short* Hb0 = (unsigned short*)ws;
    unsigned short* Hb1 = (unsigned short*)(ws + HBB);
    unsigned short* WpT = (unsigned short*)(ws + 2 * HBB); // k-major bf16 weights, 8 MB
    unsigned short* dwp = (unsigned short*)(ws + 2 * HBB + (size_t)NLEVS * 2 * CC * 1024 * 2);

    prep_kernel<<<24736, 256, 0, stream>>>(x, emb, w1, w2, dw, Hb0, Hb1, WpT, dwp);

    const int grid = (CC / 128) * (NN / 256);   // 4 * 128 = 512 blocks = 2/CU
    for (int i = 0; i < NLEVS; ++i) {
        int d = 1 << i;
        const unsigned short* W1 = WpT + (size_t)(i * 2 + 0) * CC * 1024;
        const unsigned short* W2 = WpT + (size_t)(i * 2 + 1) * CC * 1024;
        // conv1: A=Hb0 -> Hb1
        conv_gemm<false><<<grid, 256, 0, stream>>>(Hb0, W1, b1 + i * CC, nullptr, Hb1, d);
        // conv2: A=Hb1, res=Hb0 (bf16), out=Hb0 (in place, lane-owned)
        conv_gemm<true><<<grid, 256, 0, stream>>>(Hb1, W2, b2 + i * CC, Hb0, Hb0, d);
    }
    decode_kernel<<<NN / 64, 256, 0, stream>>>(Hb0, dwp, db, mask, out);
}